// Round 1
// baseline (317.595 us; speedup 1.0000x reference)
//
#include <hip/hip_runtime.h>

#define B_ 8
#define T_ 16
#define D_ 1536
#define N_ 12
#define KH_ 2
#define G_ 6
#define H_ 128
#define S_ 8192
#define NCHUNK 16

// ---------------------------------------------------------------------------
// Generic 128-row GEMM with split-K and atomic accumulation.
// A: (128, Kdim) lda; B: (Kdim, Ncols) ldb row-major; C(128, ldc) += A*B.
// grid.x = Ncols/64, grid.y = ksplits (Kdim/ksplits must be a multiple of 32)
// ---------------------------------------------------------------------------
__global__ __launch_bounds__(256) void gemm128_atomic(
    const float* __restrict__ A, int lda,
    const float* __restrict__ B, int ldb,
    float* __restrict__ C, int ldc, int Kdim)
{
    __shared__ float As[128][33];
    __shared__ float Bs[32][64];
    const int tid  = threadIdx.x;
    const int col0 = blockIdx.x * 64;
    const int ksz  = Kdim / gridDim.y;
    const int k0   = blockIdx.y * ksz;
    const int tx   = tid & 7, ty = tid >> 3;

    float acc[4][8];
#pragma unroll
    for (int r = 0; r < 4; ++r)
#pragma unroll
        for (int j = 0; j < 8; ++j) acc[r][j] = 0.f;

    for (int kk = 0; kk < ksz; kk += 32) {
#pragma unroll
        for (int i = 0; i < 16; ++i) {
            int e = tid + i * 256;
            int r = e >> 5, c = e & 31;
            As[r][c] = A[(size_t)r * lda + k0 + kk + c];
        }
#pragma unroll
        for (int i = 0; i < 8; ++i) {
            int e = tid + i * 256;
            int r = e >> 6, c = e & 63;
            Bs[r][c] = B[(size_t)(k0 + kk + r) * ldb + col0 + c];
        }
        __syncthreads();
#pragma unroll
        for (int kb = 0; kb < 32; ++kb) {
            float av[4];
            av[0] = As[ty][kb]; av[1] = As[ty + 32][kb];
            av[2] = As[ty + 64][kb]; av[3] = As[ty + 96][kb];
            float4 b0 = *(float4*)&Bs[kb][tx * 8];
            float4 b1 = *(float4*)&Bs[kb][tx * 8 + 4];
            float bv[8] = {b0.x, b0.y, b0.z, b0.w, b1.x, b1.y, b1.z, b1.w};
#pragma unroll
            for (int r = 0; r < 4; ++r)
#pragma unroll
                for (int j = 0; j < 8; ++j) acc[r][j] += av[r] * bv[j];
        }
        __syncthreads();
    }
#pragma unroll
    for (int r = 0; r < 4; ++r) {
        int row = ty + 32 * r;
#pragma unroll
        for (int j = 0; j < 8; ++j)
            atomicAdd(&C[(size_t)row * ldc + col0 + tx * 8 + j], acc[r][j]);
    }
}

// ---------------------------------------------------------------------------
// Bias add + RoPE. One block per (b,t) row. Writes rotated q, k and biased v.
// ---------------------------------------------------------------------------
__global__ __launch_bounds__(128) void rope_kernel(
    const float* __restrict__ q_acc, const float* __restrict__ k_acc,
    const float* __restrict__ v_acc,
    const float* __restrict__ bq, const float* __restrict__ bk,
    const float* __restrict__ bv,
    const int* __restrict__ seg, const int* __restrict__ start_ind,
    const int* __restrict__ curp,
    float* __restrict__ q_rope, float* __restrict__ k_new,
    float* __restrict__ v_new)
{
    const int row = blockIdx.x;
    const int b = row >> 4, t = row & 15;
    const int tid = threadIdx.x;
    __shared__ float sc[64][2];

    const int CUR = curp[0];
    int c = 0;
    for (int tt = 0; tt <= t; ++tt) c += (seg[b * T_ + tt] != 0) ? 1 : 0;
    int pos = max(c - 1, 0) + CUR;

    if (tid < 64) {
        float frac = (2.0f * tid) / (float)H_;
        float ts = expf(frac * logf(1000000.0f));
        float ang = (float)pos / ts;
        sc[tid][0] = sinf(ang);
        sc[tid][1] = cosf(ang);
    }
    __syncthreads();

    // q: 12 heads
    for (int e = tid; e < N_ * 64; e += 128) {
        int n = e >> 6, i = e & 63;
        size_t base = (size_t)row * (N_ * H_) + n * H_;
        float x1 = q_acc[base + i] + bq[n * H_ + i];
        float x2 = q_acc[base + i + 64] + bq[n * H_ + i + 64];
        float s = sc[i][0], co = sc[i][1];
        q_rope[base + i]      = x1 * co - x2 * s;
        q_rope[base + i + 64] = x2 * co + x1 * s;
    }
    // k: 2 heads
    for (int e = tid; e < KH_ * 64; e += 128) {
        int n = e >> 6, i = e & 63;
        size_t base = (size_t)row * (KH_ * H_) + n * H_;
        float x1 = k_acc[base + i] + bk[n * H_ + i];
        float x2 = k_acc[base + i + 64] + bk[n * H_ + i + 64];
        float s = sc[i][0], co = sc[i][1];
        k_new[base + i]      = x1 * co - x2 * s;
        k_new[base + i + 64] = x2 * co + x1 * s;
    }
    // v: bias only
    for (int e = tid; e < KH_ * H_; e += 128)
        v_new[(size_t)row * (KH_ * H_) + e] =
            v_acc[(size_t)row * (KH_ * H_) + e] + bv[e];
}

// ---------------------------------------------------------------------------
// Flash-style split-KV attention.
// grid = (NCHUNK, B, KH), block = 512 (8 waves).
// Wave w handles 12 queries (qi = w*12 .. +11), qi = t*G + g.
// QK: lane = (key 0..31, qhalf 0..1); PV: lane = dim-pair.
// Writes per-chunk partials: [chunk][b][kh][qi][132] = {m, l, acc[128], pad}
// ---------------------------------------------------------------------------
__global__ __launch_bounds__(512, 1) void attn_kernel(
    const float* __restrict__ q_rope, const float* __restrict__ k_new,
    const float* __restrict__ v_new,
    const float* __restrict__ k_cache, const float* __restrict__ v_cache,
    const int* __restrict__ seg, const int* __restrict__ start_ind,
    const int* __restrict__ curp,
    float* __restrict__ part)
{
    const int chunk = blockIdx.x, b = blockIdx.y, kh = blockIdx.z;
    const int tid = threadIdx.x;
    const int lane = tid & 63, w = tid >> 6;
    const float scale = 0.088388347648318447f; // 128^-0.5

    const int CUR = curp[0];
    const int SPAN = CUR + T_;
    const int CH = (SPAN + NCHUNK - 1) / NCHUNK;
    const int s0 = chunk * CH;
    const int s1 = min(s0 + CH, SPAN);

    int st = start_ind[b];
    if (st < 0) {
        st = 0;
        for (int tt = 0; tt < T_; ++tt) {
            if (seg[b * T_ + tt] != 0) { st = tt; break; }
        }
    }

    __shared__ float4 q4[96][32];    // 48 KiB
    __shared__ float4 k4[32][33];    // [d4][key], padded; 16.5 KiB
    __shared__ float  v_s[32][128];  // 16 KiB
    __shared__ float  p_s[96][36];   // 13.5 KiB
    __shared__ float  r_s[96];

    // stage all 96 q vectors
    for (int e = tid; e < 96 * 32; e += 512) {
        int qi = e >> 5, d4 = e & 31;
        int t = qi / G_, g = qi - t * G_;
        q4[qi][d4] = *(const float4*)&q_rope[
            ((((size_t)b * T_ + t) * N_) + kh * G_ + g) * H_ + d4 * 4];
    }

    const int qbase = w * 12;
    const int key = lane & 31, qs = lane >> 5;
    const int tq = w * 2 + qs;               // query t for this lane's half
    const int segid = seg[b * T_ + tq];
    const int qpos = CUR + tq - st;

    float m[6], l[6];
    float2 acc[12];
#pragma unroll
    for (int j = 0; j < 6; ++j) { m[j] = -__builtin_inff(); l[j] = 0.f; }
#pragma unroll
    for (int j = 0; j < 12; ++j) { acc[j].x = 0.f; acc[j].y = 0.f; }

    for (int stile = s0; stile < s1; stile += 32) {
        const int nk = min(32, s1 - stile);
        __syncthreads(); // protect k4/v_s/p_s from previous tile's readers
        // stage K tile (transposed-by-4) and V tile
        for (int e = tid; e < 32 * 32; e += 512) {
            int ky = e >> 5, d4 = e & 31;
            int s = stile + ky;
            float4 val = {0.f, 0.f, 0.f, 0.f};
            if (s < s1) {
                const float* src = (s < CUR)
                    ? &k_cache[((((size_t)b * S_ + s) * KH_) + kh) * H_ + d4 * 4]
                    : &k_new[((((size_t)b * T_ + (s - CUR)) * KH_) + kh) * H_ + d4 * 4];
                val = *(const float4*)src;
            }
            k4[d4][ky] = val;
        }
        for (int e = tid; e < 32 * 32; e += 512) {
            int ky = e >> 5, d4 = e & 31;
            int s = stile + ky;
            float4 val = {0.f, 0.f, 0.f, 0.f};
            if (s < s1) {
                const float* src = (s < CUR)
                    ? &v_cache[((((size_t)b * S_ + s) * KH_) + kh) * H_ + d4 * 4]
                    : &v_new[((((size_t)b * T_ + (s - CUR)) * KH_) + kh) * H_ + d4 * 4];
                val = *(const float4*)src;
            }
            *(float4*)&v_s[ky][d4 * 4] = val;
        }
        __syncthreads();

        // ---- QK^T: lane computes 6 logits for (its key, its query half) ----
        float logit[6];
#pragma unroll
        for (int j = 0; j < 6; ++j) logit[j] = 0.f;
#pragma unroll 4
        for (int d4 = 0; d4 < 32; ++d4) {
            float4 kv = k4[d4][key];
#pragma unroll
            for (int j = 0; j < 6; ++j) {
                float4 qq = q4[qbase + qs * 6 + j][d4];
                logit[j] += qq.x * kv.x + qq.y * kv.y + qq.z * kv.z + qq.w * kv.w;
            }
        }

        const int s = stile + key;
        const bool sval = (key < nk);
        const int kvseg = (s >= st && s < SPAN) ? 1 : 0;
        const int kpos = s - st;
#pragma unroll
        for (int j = 0; j < 6; ++j) {
            int qi = qbase + qs * 6 + j;
            bool valid = sval && (kpos <= qpos) && (kvseg == segid);
            float lg = valid ? logit[j] * scale : -__builtin_inff();
            // max over the 32 lanes of this half
            float tm = lg;
            tm = fmaxf(tm, __shfl_xor(tm, 16));
            tm = fmaxf(tm, __shfl_xor(tm, 8));
            tm = fmaxf(tm, __shfl_xor(tm, 4));
            tm = fmaxf(tm, __shfl_xor(tm, 2));
            tm = fmaxf(tm, __shfl_xor(tm, 1));
            float mn = fmaxf(m[j], tm);
            float r, p;
            if (mn == -__builtin_inff()) { r = 0.f; p = 0.f; }
            else {
                r = (m[j] == -__builtin_inff()) ? 0.f : expf(m[j] - mn);
                p = (lg == -__builtin_inff()) ? 0.f : expf(lg - mn);
            }
            float ps = p;
            ps += __shfl_xor(ps, 16);
            ps += __shfl_xor(ps, 8);
            ps += __shfl_xor(ps, 4);
            ps += __shfl_xor(ps, 2);
            ps += __shfl_xor(ps, 1);
            l[j] = l[j] * r + ps;
            m[j] = mn;
            p_s[qi][key] = p;
            if (key == 0) r_s[qi] = r;
        }
        __syncthreads();

        // ---- PV: lane = dim pair (2*lane, 2*lane+1) for all 12 queries ----
#pragma unroll
        for (int j2 = 0; j2 < 12; ++j2) {
            float r = r_s[qbase + j2];
            acc[j2].x *= r; acc[j2].y *= r;
        }
#pragma unroll
        for (int sg = 0; sg < 8; ++sg) {
            float2 vv[4];
#pragma unroll
            for (int u = 0; u < 4; ++u)
                vv[u] = *(float2*)&v_s[sg * 4 + u][2 * lane];
#pragma unroll
            for (int j2 = 0; j2 < 12; ++j2) {
                float4 p4 = *(float4*)&p_s[qbase + j2][sg * 4];
                acc[j2].x += p4.x * vv[0].x + p4.y * vv[1].x + p4.z * vv[2].x + p4.w * vv[3].x;
                acc[j2].y += p4.x * vv[0].y + p4.y * vv[1].y + p4.z * vv[2].y + p4.w * vv[3].y;
            }
        }
    }

    // ---- write partials ----
#pragma unroll
    for (int j = 0; j < 6; ++j) {
        int qi = qbase + qs * 6 + j;
        size_t base = ((((size_t)chunk * B_ + b) * KH_ + kh) * 96 + qi) * 132;
        if (key == 0) { part[base] = m[j]; part[base + 1] = l[j]; }
    }
#pragma unroll
    for (int j2 = 0; j2 < 12; ++j2) {
        int qi = qbase + j2;
        size_t base = ((((size_t)chunk * B_ + b) * KH_ + kh) * 96 + qi) * 132;
        *(float2*)&part[base + 2 + 2 * lane] = acc[j2];
    }
}

// ---------------------------------------------------------------------------
// Combine per-chunk partials -> qkv (b,t,N,H) flat (row, n*128+h)
// ---------------------------------------------------------------------------
__global__ __launch_bounds__(256) void combine_kernel(
    const float* __restrict__ part, float* __restrict__ qkv)
{
    const int row = blockIdx.x;
    const int b = row >> 4, t = row & 15;
    const int tid = threadIdx.x;
    const int half = tid >> 7, h = tid & 127;
    const size_t cstride = (size_t)B_ * KH_ * 96 * 132;

    for (int nb = 0; nb < N_; nb += 2) {
        int n = nb + half;
        int kh = n / G_, g = n - kh * G_;
        int qi = t * G_ + g;
        size_t base0 = (((size_t)b * KH_ + kh) * 96 + qi) * 132;
        float M = -__builtin_inff();
        for (int c = 0; c < NCHUNK; ++c)
            M = fmaxf(M, part[base0 + c * cstride]);
        float den = 0.f, num = 0.f;
        for (int c = 0; c < NCHUNK; ++c) {
            float mc = part[base0 + c * cstride];
            float e = (M == -__builtin_inff() || mc == -__builtin_inff())
                          ? 0.f : expf(mc - M);
            den += e * part[base0 + c * cstride + 1];
            num += e * part[base0 + c * cstride + 2 + h];
        }
        qkv[(size_t)row * (N_ * H_) + n * H_ + h] = (den > 0.f) ? num / den : 0.f;
    }
}

// ---------------------------------------------------------------------------
extern "C" void kernel_launch(void* const* d_in, const int* in_sizes, int n_in,
                              void* d_out, int out_size, void* d_ws, size_t ws_size,
                              hipStream_t stream)
{
    (void)in_sizes; (void)n_in; (void)out_size; (void)ws_size;
    const float* x       = (const float*)d_in[0];
    const float* k_cache = (const float*)d_in[1];
    const float* v_cache = (const float*)d_in[2];
    const float* wq      = (const float*)d_in[3];
    const float* bq      = (const float*)d_in[4];
    const float* wk      = (const float*)d_in[5];
    const float* bk      = (const float*)d_in[6];
    const float* wv      = (const float*)d_in[7];
    const float* bv      = (const float*)d_in[8];
    const float* wo      = (const float*)d_in[9];
    const int*   seg     = (const int*)d_in[10];
    const int*   start_i = (const int*)d_in[11];
    const int*   curp    = (const int*)d_in[12];
    float* out = (float*)d_out;
    float* ws  = (float*)d_ws;

    const size_t QSZ = (size_t)B_ * T_ * N_ * H_;   // 196608
    const size_t KSZ = (size_t)B_ * T_ * KH_ * H_;  // 32768
    float* q_acc  = ws;
    float* k_acc  = q_acc + QSZ;
    float* v_acc  = k_acc + KSZ;
    float* q_rope = v_acc + KSZ;
    float* k_new  = q_rope + QSZ;
    float* v_new  = k_new + KSZ;
    float* part   = v_new + KSZ;
    const size_t PSZ = (size_t)NCHUNK * B_ * KH_ * 96 * 132; // 3,244,032
    float* qkv    = part + PSZ;

    hipMemsetAsync(q_acc, 0, (QSZ + 2 * KSZ) * sizeof(float), stream);

    // projections (split-K atomic)
    gemm128_atomic<<<dim3(24, 8), 256, 0, stream>>>(x, D_, wq, N_ * H_, q_acc, N_ * H_, D_);
    gemm128_atomic<<<dim3(4, 8), 256, 0, stream>>>(x, D_, wk, KH_ * H_, k_acc, KH_ * H_, D_);
    gemm128_atomic<<<dim3(4, 8), 256, 0, stream>>>(x, D_, wv, KH_ * H_, v_acc, KH_ * H_, D_);

    rope_kernel<<<B_ * T_, 128, 0, stream>>>(q_acc, k_acc, v_acc, bq, bk, bv,
                                             seg, start_i, curp,
                                             q_rope, k_new, v_new);

    attn_kernel<<<dim3(NCHUNK, B_, KH_), 512, 0, stream>>>(
        q_rope, k_new, v_new, k_cache, v_cache, seg, start_i, curp, part);

    combine_kernel<<<B_ * T_, 256, 0, stream>>>(part, qkv);

    hipMemsetAsync(out, 0, (size_t)B_ * T_ * D_ * sizeof(float), stream);
    gemm128_atomic<<<dim3(24, 8), 256, 0, stream>>>(qkv, N_ * H_, wo, D_, out, D_, D_);
}